// Round 11
// baseline (485.166 us; speedup 1.0000x reference)
//
#include <hip/hip_runtime.h>
#include <hip/hip_bf16.h>
#include <stdint.h>

#define NHEADS 16
#define HDIM 80
#define CHUNK 2048
#define QSCALE 0.11180339887498949f   /* 80^-0.5 */
#define L2E 1.4426950408889634f

typedef __bf16 bf16x8 __attribute__((ext_vector_type(8)));
typedef float f32x4 __attribute__((ext_vector_type(4)));

__device__ __forceinline__ unsigned short f2bf(float f) {
  union { float f; unsigned u; } x; x.f = f;
  unsigned r = (x.u + 0x7fffu + ((x.u >> 16) & 1u)) >> 16;
  return (unsigned short)r;
}

__device__ __forceinline__ float fexp2(float x) {   // raw v_exp_f32
  float r;
  asm("v_exp_f32 %0, %1" : "=v"(r) : "v"(x));
  return r;
}

__device__ __forceinline__ void gload16(const void* g, void* lds) {
  __builtin_amdgcn_global_load_lds((const __attribute__((address_space(1))) void*)g,
                                   (__attribute__((address_space(3))) void*)lds, 16, 0, 0);
}

/* ---------------- fp32 -> bf16 convert ---------------- */
__global__ __launch_bounds__(256) void cvt_f32_bf16(const float* __restrict__ in,
                                                    unsigned short* __restrict__ out, int n4) {
  int i = blockIdx.x * 256 + threadIdx.x;
  int stride = gridDim.x * 256;
  for (; i < n4; i += stride) {
    float4 v = reinterpret_cast<const float4*>(in)[i];
    ushort4 o;
    o.x = f2bf(v.x); o.y = f2bf(v.y); o.z = f2bf(v.z); o.w = f2bf(v.w);
    reinterpret_cast<ushort4*>(out)[i] = o;
  }
}

/* ---------------- bf16 GEMM: C = A * B^T + bias ---------------- */
__global__ __launch_bounds__(256) void gemm_bt(
    const unsigned short* __restrict__ A, const unsigned short* __restrict__ B,
    const float* __restrict__ bias, unsigned short* __restrict__ C,
    float* __restrict__ Cf,
    int M, int N, int K, int lda, int scaleN, float scaleVal)
{
  __shared__ unsigned short Ash[128 * 32];
  __shared__ unsigned short Bsh[128 * 32];
  const int tid = threadIdx.x;
  const int lane = tid & 63;
  const int w = tid >> 6;
  const int wr = w >> 1, wc = w & 1;
  const int l15 = lane & 15, lq = lane >> 4;
  const long bm = (long)blockIdx.y * 128;
  const long bn = (long)blockIdx.x * 128;

  f32x4 acc[4][4];
#pragma unroll
  for (int i = 0; i < 4; i++)
#pragma unroll
    for (int j = 0; j < 4; j++) acc[i][j] = f32x4{0.f, 0.f, 0.f, 0.f};

  const int srow = lane >> 2;
  const int scol = (lane & 3) * 8;

  for (long k0 = 0; k0 < K; k0 += 32) {
    __syncthreads();
#pragma unroll
    for (int i = 0; i < 2; i++) {
      gload16(A + (bm + w * 32 + i * 16 + srow) * (long)lda + k0 + scol,
              (char*)Ash + (w * 2 + i) * 1024);
      gload16(B + (bn + w * 32 + i * 16 + srow) * (long)K + k0 + scol,
              (char*)Bsh + (w * 2 + i) * 1024);
    }
    __syncthreads();
    bf16x8 af[4], bfr[4];
#pragma unroll
    for (int x = 0; x < 4; x++) {
      af[x]  = *reinterpret_cast<const bf16x8*>(Ash + (wr * 64 + x * 16 + l15) * 32 + lq * 8);
      bfr[x] = *reinterpret_cast<const bf16x8*>(Bsh + (wc * 64 + x * 16 + l15) * 32 + lq * 8);
    }
#pragma unroll
    for (int x = 0; x < 4; x++)
#pragma unroll
      for (int y = 0; y < 4; y++)
        acc[x][y] = __builtin_amdgcn_mfma_f32_16x16x32_bf16(af[x], bfr[y], acc[x][y], 0, 0, 0);
  }

#pragma unroll
  for (int x = 0; x < 4; x++) {
    long row0 = bm + wr * 64 + x * 16 + lq * 4;
#pragma unroll
    for (int y = 0; y < 4; y++) {
      int col = (int)bn + wc * 64 + y * 16 + l15;
      float bs = bias[col];
      float sc = (col < scaleN) ? scaleVal : 1.0f;
      if (Cf != nullptr) {
#pragma unroll
        for (int r = 0; r < 4; r++)
          Cf[(size_t)(row0 + r) * N + col] = (acc[x][y][r] + bs) * sc;
      } else {
#pragma unroll
        for (int r = 0; r < 4; r++)
          C[(size_t)(row0 + r) * N + col] = f2bf((acc[x][y][r] + bs) * sc);
      }
    }
  }
}

/* ---------------- one-shot V transpose: qkv V-cols -> vT[chp][80][2048] ---------------- */
__global__ __launch_bounds__(256) void transpose_v(
    const unsigned short* __restrict__ qkv, unsigned short* __restrict__ vt)
{
  __shared__ unsigned short Tsh[64 * 88];
  const int tid = threadIdx.x;
  const int ch = blockIdx.y >> 4, head = blockIdx.y & 15;
  const int st = blockIdx.x;
  const unsigned short* src = qkv + (size_t)(ch * CHUNK + st * 64) * 3840 + 2560 + head * HDIM;
  for (int s = tid; s < 640; s += 256) {
    int r = s / 10, c = s % 10;
    uint4 v = *reinterpret_cast<const uint4*>(src + (size_t)r * 3840 + c * 8);
    *reinterpret_cast<uint4*>(&Tsh[r * 88 + c * 8]) = v;
  }
  __syncthreads();
  unsigned short* dst = vt + ((size_t)(ch * 16 + head) * HDIM) * 2048 + st * 64;
  for (int s = tid; s < 640; s += 256) {
    int d = s >> 3, c2 = s & 7;
    unsigned short ubuf[8];
#pragma unroll
    for (int e = 0; e < 8; e++) ubuf[e] = Tsh[(c2 * 8 + e) * 88 + d];
    *reinterpret_cast<uint4*>(dst + (size_t)d * 2048 + c2 * 8) = *reinterpret_cast<const uint4*>(ubuf);
  }
}

/* ---------------- flash attention (streaming softmax, post-PV rescale) ----------------
   Register-lean streaming structure (no live s[2][4]); total demand
   ~124-132 regs. launch_bounds(256,4) caps total at 128 -> 4 waves/SIMD
   (occupancy cliff at 128: 65..128 regs = 4 waves, 129.. = 2 waves).
   Round-7's (256,4) spill disaster predated the s-array removal; demand
   is now ~4 regs over the 80-arch cap -> allocator remat, not spill.
   LDS 40960 x 4 blocks = exactly 160 KiB/CU. */
__global__ __launch_bounds__(256, 4) void attn_kernel(
    const unsigned short* __restrict__ qkv, const unsigned short* __restrict__ vt,
    unsigned short* __restrict__ outq)
{
  __shared__ char Kbuf[10240];                  // K tile [64][80], linear
  __shared__ char Vbuf[12288];                  // V tile [80][72]
  __shared__ unsigned short Psh[4][32 * 72];    // per-wave P

  const int tid = threadIdx.x;
  const int lane = tid & 63;
  const int w = tid >> 6;
  const int l15 = lane & 15, lq = lane >> 4;

  // XCD-aware decode: all 16 q-tiles of one (ch,head) land on one XCD
  const int b = blockIdx.x;
  const int qt = (b >> 3) & 15;
  const int chp = (b & 7) * 8 + (b >> 7);   // 0..63 = ch*16+head
  const int ch = chp >> 4;
  const int head = chp & 15;

  const size_t rs = 3840;
  const unsigned short* qbase = qkv + (size_t)(ch * CHUNK) * rs + head * HDIM;
  const char* kbase = (const char*)(qbase + 1280);
  const char* vbase = (const char*)(vt + (size_t)chp * HDIM * 2048);

  // staging geometry: per-lane 32-bit byte offsets (base kept in SGPR)
  int kgo[3]; bool kact[3];
  const int koff0 = w * 1024;                    // LDS offsets wave-uniform
#pragma unroll
  for (int j = 0; j < 3; j++) {
    int c = w + 4 * j;
    kact[j] = (c < 10);
    int cc = kact[j] ? c : 0;
    int s = cc * 64 + lane;
    kgo[j] = (s / 10) * 7680 + (s % 10) * 16;
  }
  int vgo[3];
  const int vw = (w + 2) & 3;
#pragma unroll
  for (int j = 0; j < 3; j++) {
    int c = vw + 4 * j;                          // V chunk index 0..11
    int s2 = c * 64 + lane;
    if (s2 > 719) s2 = 719;
    int d = s2 / 9, u = s2 % 9;
    int ue = (u == 8) ? 0 : u;
    vgo[j] = d * 4096 + ue * 16;
  }

  // Q fragments in registers
  const int qr0 = qt * 128 + w * 32;
  bf16x8 qa[2][2], qa2[2];
#pragma unroll
  for (int qf = 0; qf < 2; qf++) {
    const unsigned short* qrow = qbase + (size_t)(qr0 + qf * 16 + l15) * rs;
    qa[qf][0] = *reinterpret_cast<const bf16x8*>(qrow + lq * 8);
    qa[qf][1] = *reinterpret_cast<const bf16x8*>(qrow + 32 + lq * 8);
    if (lq < 2) qa2[qf] = *reinterpret_cast<const bf16x8*>(qrow + 64 + lq * 8);
    else        qa2[qf] = bf16x8{};
  }

  // ones B-fragment for the sum column
  bf16x8 onesb;
  {
    __bf16 o = (l15 == 0) ? (__bf16)1.0f : (__bf16)0.0f;
    onesb = bf16x8{o, o, o, o, o, o, o, o};
  }

  f32x4 acc[2][6];
#pragma unroll
  for (int qf = 0; qf < 2; qf++)
#pragma unroll
    for (int df = 0; df < 6; df++) acc[qf][df] = f32x4{0.f, 0.f, 0.f, 0.f};
  float mst[2][4];
#pragma unroll
  for (int qf = 0; qf < 2; qf++)
#pragma unroll
    for (int r = 0; r < 4; r++) mst[qf][r] = 16.0f;   // finite upper-bound init

  // prologue: stage K0, V0
#pragma unroll
  for (int j = 0; j < 3; j++)
    if (kact[j]) gload16(kbase + kgo[j], Kbuf + koff0 + j * 4096);
#pragma unroll
  for (int j = 0; j < 3; j++) gload16(vbase + vgo[j], Vbuf + vw * 1024 + j * 4096);
  __syncthreads();

  for (int kt = 0; kt < CHUNK; kt += 64) {
    // QK^T + streaming P (computed with current mst; rescale deferred post-PV)
    float tmax[2][4];
#pragma unroll
    for (int qf = 0; qf < 2; qf++)
#pragma unroll
      for (int r = 0; r < 4; r++) tmax[qf][r] = -1e30f;

    const unsigned short* Ksh = (const unsigned short*)Kbuf;
#pragma unroll
    for (int kf = 0; kf < 4; kf++) {
      const unsigned short* kr = Ksh + (kf * 16 + l15) * 80;
      bf16x8 kb0 = *reinterpret_cast<const bf16x8*>(kr + lq * 8);
      bf16x8 kb1 = *reinterpret_cast<const bf16x8*>(kr + 32 + lq * 8);
      bf16x8 kb2 = (lq < 2) ? *reinterpret_cast<const bf16x8*>(kr + 64 + lq * 8) : bf16x8{};
#pragma unroll
      for (int qf = 0; qf < 2; qf++) {
        f32x4 sv = f32x4{0.f, 0.f, 0.f, 0.f};
        sv = __builtin_amdgcn_mfma_f32_16x16x32_bf16(qa[qf][0], kb0, sv, 0, 0, 0);
        sv = __builtin_amdgcn_mfma_f32_16x16x32_bf16(qa[qf][1], kb1, sv, 0, 0, 0);
        sv = __builtin_amdgcn_mfma_f32_16x16x32_bf16(qa2[qf], kb2, sv, 0, 0, 0);
#pragma unroll
        for (int r = 0; r < 4; r++) {
          tmax[qf][r] = fmaxf(tmax[qf][r], sv[r]);
          float p = fexp2((sv[r] - mst[qf][r]) * L2E);
          unsigned pk;
          asm("v_cvt_pk_bf16_f32 %0, %1, %2" : "=v"(pk) : "v"(p), "v"(p));
          Psh[w][(qf * 16 + lq * 4 + r) * 72 + kf * 16 + l15] = (unsigned short)pk;
        }
      }
    }

    // rescale decision (applied after PV: acc_new = alpha*(acc_old + P*V))
    bool need = false;
#pragma unroll
    for (int qf = 0; qf < 2; qf++)
#pragma unroll
      for (int r = 0; r < 4; r++)
        need = need || (tmax[qf][r] > mst[qf][r] + 8.0f);
    const bool resc = __any(need);
    float alpha[2][4];
    if (resc) {
#pragma unroll
      for (int m = 1; m < 16; m <<= 1)
#pragma unroll
        for (int qf = 0; qf < 2; qf++)
#pragma unroll
          for (int r = 0; r < 4; r++)
            tmax[qf][r] = fmaxf(tmax[qf][r], __shfl_xor(tmax[qf][r], m, 64));
#pragma unroll
      for (int qf = 0; qf < 2; qf++)
#pragma unroll
        for (int r = 0; r < 4; r++) {
          float mnew = fmaxf(mst[qf][r], tmax[qf][r]);
          alpha[qf][r] = fexp2((mst[qf][r] - mnew) * L2E);
          mst[qf][r] = mnew;
        }
    }

    __syncthreads();   // B1: all waves done reading K(t); drains V(t) loads

    // issue K(t+1); hides under PV
    if (kt + 64 < CHUNK) {
      const int ktB = (kt + 64) * 7680;
#pragma unroll
      for (int j = 0; j < 3; j++)
        if (kact[j]) gload16(kbase + kgo[j] + ktB, Kbuf + koff0 + j * 4096);
    }

    // PV (+ sum column)
    const unsigned short* Vsh = (const unsigned short*)Vbuf;
#pragma unroll
    for (int ks = 0; ks < 2; ks++) {
      bf16x8 pa[2];
#pragma unroll
      for (int qf = 0; qf < 2; qf++)
        pa[qf] = *reinterpret_cast<const bf16x8*>(&Psh[w][(qf * 16 + l15) * 72 + ks * 32 + lq * 8]);
#pragma unroll
      for (int df = 0; df < 5; df++) {
        bf16x8 vb = *reinterpret_cast<const bf16x8*>(&Vsh[(df * 16 + l15) * 72 + ks * 32 + lq * 8]);
#pragma unroll
        for (int qf = 0; qf < 2; qf++)
          acc[qf][df] = __builtin_amdgcn_mfma_f32_16x16x32_bf16(pa[qf], vb, acc[qf][df], 0, 0, 0);
      }
#pragma unroll
      for (int qf = 0; qf < 2; qf++)
        acc[qf][5] = __builtin_amdgcn_mfma_f32_16x16x32_bf16(pa[qf], onesb, acc[qf][5], 0, 0, 0);
    }

    // deferred rescale (rare)
    if (resc) {
#pragma unroll
      for (int qf = 0; qf < 2; qf++)
#pragma unroll
        for (int df = 0; df < 6; df++)
#pragma unroll
          for (int r = 0; r < 4; r++) acc[qf][df][r] *= alpha[qf][r];
    }

    __syncthreads();   // B2: all waves done reading V(t); drains K(t+1) loads

    // issue V(t+1); hides under next tile's QK^T + softmax
    if (kt + 64 < CHUNK) {
      const int ktV = (kt + 64) * 2;
#pragma unroll
      for (int j = 0; j < 3; j++)
        gload16(vbase + vgo[j] + ktV, Vbuf + vw * 1024 + j * 4096);
    }
  }

  // epilogue: out = acc / sum
  unsigned short* obase = outq + (size_t)(ch * CHUNK) * rs + head * HDIM;
#pragma unroll
  for (int qf = 0; qf < 2; qf++) {
    float inv[4];
#pragma unroll
    for (int r = 0; r < 4; r++) inv[r] = 1.0f / __shfl(acc[qf][5][r], lq * 16, 64);
#pragma unroll
    for (int df = 0; df < 5; df++) {
      int col = df * 16 + l15;
#pragma unroll
      for (int r = 0; r < 4; r++) {
        float v = acc[qf][df][r] * inv[r];
        obase[(size_t)(qr0 + qf * 16 + lq * 4 + r) * rs + col] = f2bf(v);
      }
    }
  }
}

extern "C" void kernel_launch(void* const* d_in, const int* in_sizes, int n_in,
                              void* d_out, int out_size, void* d_ws, size_t ws_size,
                              hipStream_t stream) {
  const float* hs    = (const float*)d_in[0];   // [8192][1280]
  const float* qkvw  = (const float*)d_in[2];   // [3840][1280]
  const float* qkvb  = (const float*)d_in[3];   // [3840]
  const float* projw = (const float*)d_in[4];   // [1280][1280]
  const float* projb = (const float*)d_in[5];   // [1280]

  char* ws = (char*)d_ws;
  unsigned short* hs_bf    = (unsigned short*)ws;                         // 20,971,520 B
  unsigned short* vT       = hs_bf;                                       // alias (hs_bf dead after QKV gemm)
  unsigned short* qkvw_bf  = (unsigned short*)(ws + 20971520);            //  9,830,400 B
  unsigned short* projw_bf = (unsigned short*)(ws + 20971520 + 9830400);  //  3,276,800 B
  unsigned short* qkv_bf   = (unsigned short*)(ws + 20971520 + 9830400 + 3276800); // 62,914,560 B

  cvt_f32_bf16<<<2048, 256, 0, stream>>>(hs,    hs_bf,    8192 * 1280 / 4);
  cvt_f32_bf16<<<1024, 256, 0, stream>>>(qkvw,  qkvw_bf,  3840 * 1280 / 4);
  cvt_f32_bf16<<<512,  256, 0, stream>>>(projw, projw_bf, 1280 * 1280 / 4);

  // qkv = hs @ qkv_w^T + qkv_b ; q cols pre-scaled (bf16 out)
  gemm_bt<<<dim3(30, 64), 256, 0, stream>>>(hs_bf, qkvw_bf, qkvb, qkv_bf, nullptr,
                                            8192, 3840, 1280, 1280, 1280, QSCALE);
  // one-shot V transpose into hs_bf region (now dead)
  transpose_v<<<dim3(32, 64), 256, 0, stream>>>(qkv_bf, vT);
  // attention; output overwrites Q-columns of qkv_bf (XCD-swizzled 1-D grid)
  attn_kernel<<<dim3(1024), 256, 0, stream>>>(qkv_bf, vT, qkv_bf);
  // out = attn @ proj_w^T + proj_b (fp32 out), A has row stride 3840
  gemm_bt<<<dim3(10, 64), 256, 0, stream>>>(qkv_bf, projw_bf, projb,
                                            nullptr, (float*)d_out,
                                            8192, 1280, 1280, 3840, 0, 1.0f);
}

// Round 12
// 347.901 us; speedup vs baseline: 1.3946x; 1.3946x over previous
//
#include <hip/hip_runtime.h>
#include <hip/hip_bf16.h>
#include <stdint.h>

#define NHEADS 16
#define HDIM 80
#define CHUNK 2048
#define QSCALE 0.11180339887498949f   /* 80^-0.5 */
#define L2E 1.4426950408889634f

typedef __bf16 bf16x8 __attribute__((ext_vector_type(8)));
typedef float f32x4 __attribute__((ext_vector_type(4)));

__device__ __forceinline__ unsigned short f2bf(float f) {
  union { float f; unsigned u; } x; x.f = f;
  unsigned r = (x.u + 0x7fffu + ((x.u >> 16) & 1u)) >> 16;
  return (unsigned short)r;
}

__device__ __forceinline__ float fexp2(float x) {   // raw v_exp_f32
  float r;
  asm("v_exp_f32 %0, %1" : "=v"(r) : "v"(x));
  return r;
}

__device__ __forceinline__ void gload16(const void* g, void* lds) {
  __builtin_amdgcn_global_load_lds((const __attribute__((address_space(1))) void*)g,
                                   (__attribute__((address_space(3))) void*)lds, 16, 0, 0);
}

/* ---------------- fp32 -> bf16 convert ---------------- */
__global__ __launch_bounds__(256) void cvt_f32_bf16(const float* __restrict__ in,
                                                    unsigned short* __restrict__ out, int n4) {
  int i = blockIdx.x * 256 + threadIdx.x;
  int stride = gridDim.x * 256;
  for (; i < n4; i += stride) {
    float4 v = reinterpret_cast<const float4*>(in)[i];
    ushort4 o;
    o.x = f2bf(v.x); o.y = f2bf(v.y); o.z = f2bf(v.z); o.w = f2bf(v.w);
    reinterpret_cast<ushort4*>(out)[i] = o;
  }
}

/* ---------------- bf16 GEMM: C = A * B^T + bias ---------------- */
__global__ __launch_bounds__(256) void gemm_bt(
    const unsigned short* __restrict__ A, const unsigned short* __restrict__ B,
    const float* __restrict__ bias, unsigned short* __restrict__ C,
    float* __restrict__ Cf,
    int M, int N, int K, int lda, int scaleN, float scaleVal)
{
  __shared__ unsigned short Ash[128 * 32];
  __shared__ unsigned short Bsh[128 * 32];
  const int tid = threadIdx.x;
  const int lane = tid & 63;
  const int w = tid >> 6;
  const int wr = w >> 1, wc = w & 1;
  const int l15 = lane & 15, lq = lane >> 4;
  const long bm = (long)blockIdx.y * 128;
  const long bn = (long)blockIdx.x * 128;

  f32x4 acc[4][4];
#pragma unroll
  for (int i = 0; i < 4; i++)
#pragma unroll
    for (int j = 0; j < 4; j++) acc[i][j] = f32x4{0.f, 0.f, 0.f, 0.f};

  const int srow = lane >> 2;
  const int scol = (lane & 3) * 8;

  for (long k0 = 0; k0 < K; k0 += 32) {
    __syncthreads();
#pragma unroll
    for (int i = 0; i < 2; i++) {
      gload16(A + (bm + w * 32 + i * 16 + srow) * (long)lda + k0 + scol,
              (char*)Ash + (w * 2 + i) * 1024);
      gload16(B + (bn + w * 32 + i * 16 + srow) * (long)K + k0 + scol,
              (char*)Bsh + (w * 2 + i) * 1024);
    }
    __syncthreads();
    bf16x8 af[4], bfr[4];
#pragma unroll
    for (int x = 0; x < 4; x++) {
      af[x]  = *reinterpret_cast<const bf16x8*>(Ash + (wr * 64 + x * 16 + l15) * 32 + lq * 8);
      bfr[x] = *reinterpret_cast<const bf16x8*>(Bsh + (wc * 64 + x * 16 + l15) * 32 + lq * 8);
    }
#pragma unroll
    for (int x = 0; x < 4; x++)
#pragma unroll
      for (int y = 0; y < 4; y++)
        acc[x][y] = __builtin_amdgcn_mfma_f32_16x16x32_bf16(af[x], bfr[y], acc[x][y], 0, 0, 0);
  }

#pragma unroll
  for (int x = 0; x < 4; x++) {
    long row0 = bm + wr * 64 + x * 16 + lq * 4;
#pragma unroll
    for (int y = 0; y < 4; y++) {
      int col = (int)bn + wc * 64 + y * 16 + l15;
      float bs = bias[col];
      float sc = (col < scaleN) ? scaleVal : 1.0f;
      if (Cf != nullptr) {
#pragma unroll
        for (int r = 0; r < 4; r++)
          Cf[(size_t)(row0 + r) * N + col] = (acc[x][y][r] + bs) * sc;
      } else {
#pragma unroll
        for (int r = 0; r < 4; r++)
          C[(size_t)(row0 + r) * N + col] = f2bf((acc[x][y][r] + bs) * sc);
      }
    }
  }
}

/* ---------------- one-shot V transpose: qkv V-cols -> vT[chp][80][2048] ---------------- */
__global__ __launch_bounds__(256) void transpose_v(
    const unsigned short* __restrict__ qkv, unsigned short* __restrict__ vt)
{
  __shared__ unsigned short Tsh[64 * 88];
  const int tid = threadIdx.x;
  const int ch = blockIdx.y >> 4, head = blockIdx.y & 15;
  const int st = blockIdx.x;
  const unsigned short* src = qkv + (size_t)(ch * CHUNK + st * 64) * 3840 + 2560 + head * HDIM;
  for (int s = tid; s < 640; s += 256) {
    int r = s / 10, c = s % 10;
    uint4 v = *reinterpret_cast<const uint4*>(src + (size_t)r * 3840 + c * 8);
    *reinterpret_cast<uint4*>(&Tsh[r * 88 + c * 8]) = v;
  }
  __syncthreads();
  unsigned short* dst = vt + ((size_t)(ch * 16 + head) * HDIM) * 2048 + st * 64;
  for (int s = tid; s < 640; s += 256) {
    int d = s >> 3, c2 = s & 7;
    unsigned short ubuf[8];
#pragma unroll
    for (int e = 0; e < 8; e++) ubuf[e] = Tsh[(c2 * 8 + e) * 88 + d];
    *reinterpret_cast<uint4*>(dst + (size_t)d * 2048 + c2 * 8) = *reinterpret_cast<const uint4*>(ubuf);
  }
}

/* ---------------- flash attention: QBLK=16 per wave ----------------
   Register footprint halved vs the 32-row version: acc[6]=24 AGPR,
   Q frags 12 VGPR -> total ~95 regs, fits the 128-total granule at
   4 waves/SIMD WITHOUT allocator compression (rounds 7/11 showed the
   backend can only split 64-arch at the 128 cap; 32-row needed 80).
   4 waves x 16 rows = 64 q-rows/block; grid 2048; LDS 31744 B. */
__global__ __launch_bounds__(256, 4) void attn_kernel(
    const unsigned short* __restrict__ qkv, const unsigned short* __restrict__ vt,
    unsigned short* __restrict__ outq)
{
  __shared__ char Kbuf[10240];                  // K tile [64][80], linear
  __shared__ char Vbuf[12288];                  // V tile [80][72]
  __shared__ unsigned short Psh[4][16 * 72];    // per-wave P (16 q-rows)

  const int tid = threadIdx.x;
  const int lane = tid & 63;
  const int w = tid >> 6;
  const int l15 = lane & 15, lq = lane >> 4;

  // XCD-aware decode: all 32 q-tiles of one (ch,head) land on one XCD
  // b = [qt:5 | ... ]: xcd = b&7, qt = (b>>3)&31, chp = xcd*8 + (b>>8)
  const int b = blockIdx.x;
  const int qt = (b >> 3) & 31;
  const int chp = (b & 7) * 8 + (b >> 8);   // 0..63 = ch*16+head
  const int ch = chp >> 4;
  const int head = chp & 15;

  const size_t rs = 3840;
  const unsigned short* qbase = qkv + (size_t)(ch * CHUNK) * rs + head * HDIM;
  const char* kbase = (const char*)(qbase + 1280);
  const char* vbase = (const char*)(vt + (size_t)chp * HDIM * 2048);

  // staging geometry: per-lane 32-bit byte offsets (bases wave-uniform)
  int kgo[3]; bool kact[3];
  const int koff0 = w * 1024;
#pragma unroll
  for (int j = 0; j < 3; j++) {
    int c = w + 4 * j;
    kact[j] = (c < 10);
    int cc = kact[j] ? c : 0;
    int s = cc * 64 + lane;
    kgo[j] = (s / 10) * 7680 + (s % 10) * 16;
  }
  int vgo[3];
  const int vw = (w + 2) & 3;
#pragma unroll
  for (int j = 0; j < 3; j++) {
    int c = vw + 4 * j;
    int s2 = c * 64 + lane;
    if (s2 > 719) s2 = 719;
    int d = s2 / 9, u = s2 % 9;
    int ue = (u == 8) ? 0 : u;
    vgo[j] = d * 4096 + ue * 16;
  }

  // Q fragments (16 rows/wave): row = l15, d-slices 0..31 / 32..63 / 64..79
  const int qr0 = qt * 64 + w * 16;
  bf16x8 qa0, qa1, qa2;
  {
    const unsigned short* qrow = qbase + (size_t)(qr0 + l15) * rs;
    qa0 = *reinterpret_cast<const bf16x8*>(qrow + lq * 8);
    qa1 = *reinterpret_cast<const bf16x8*>(qrow + 32 + lq * 8);
    if (lq < 2) qa2 = *reinterpret_cast<const bf16x8*>(qrow + 64 + lq * 8);
    else        qa2 = bf16x8{};
  }

  // ones B-fragment for the sum column
  bf16x8 onesb;
  {
    __bf16 o = (l15 == 0) ? (__bf16)1.0f : (__bf16)0.0f;
    onesb = bf16x8{o, o, o, o, o, o, o, o};
  }

  f32x4 acc[6];
#pragma unroll
  for (int df = 0; df < 6; df++) acc[df] = f32x4{0.f, 0.f, 0.f, 0.f};
  float mst[4];
#pragma unroll
  for (int r = 0; r < 4; r++) mst[r] = 16.0f;   // finite upper-bound init

  // prologue: stage K0, V0
#pragma unroll
  for (int j = 0; j < 3; j++)
    if (kact[j]) gload16(kbase + kgo[j], Kbuf + koff0 + j * 4096);
#pragma unroll
  for (int j = 0; j < 3; j++) gload16(vbase + vgo[j], Vbuf + vw * 1024 + j * 4096);
  __syncthreads();

  for (int kt = 0; kt < CHUNK; kt += 64) {
    // QK^T + streaming P (with current mst; rescale deferred post-PV)
    float tmax[4];
#pragma unroll
    for (int r = 0; r < 4; r++) tmax[r] = -1e30f;

    const unsigned short* Ksh = (const unsigned short*)Kbuf;
#pragma unroll
    for (int kf = 0; kf < 4; kf++) {
      const unsigned short* kr = Ksh + (kf * 16 + l15) * 80;
      bf16x8 kb0 = *reinterpret_cast<const bf16x8*>(kr + lq * 8);
      bf16x8 kb1 = *reinterpret_cast<const bf16x8*>(kr + 32 + lq * 8);
      bf16x8 kb2 = (lq < 2) ? *reinterpret_cast<const bf16x8*>(kr + 64 + lq * 8) : bf16x8{};
      f32x4 sv = f32x4{0.f, 0.f, 0.f, 0.f};
      sv = __builtin_amdgcn_mfma_f32_16x16x32_bf16(qa0, kb0, sv, 0, 0, 0);
      sv = __builtin_amdgcn_mfma_f32_16x16x32_bf16(qa1, kb1, sv, 0, 0, 0);
      sv = __builtin_amdgcn_mfma_f32_16x16x32_bf16(qa2, kb2, sv, 0, 0, 0);
#pragma unroll
      for (int r = 0; r < 4; r++) {
        tmax[r] = fmaxf(tmax[r], sv[r]);
        float p = fexp2((sv[r] - mst[r]) * L2E);
        unsigned pk;
        asm("v_cvt_pk_bf16_f32 %0, %1, %2" : "=v"(pk) : "v"(p), "v"(p));
        Psh[w][(lq * 4 + r) * 72 + kf * 16 + l15] = (unsigned short)pk;
      }
    }

    // rescale decision (applied after PV: acc_new = alpha*(acc_old + P*V))
    bool need = false;
#pragma unroll
    for (int r = 0; r < 4; r++) need = need || (tmax[r] > mst[r] + 8.0f);
    const bool resc = __any(need);
    float alpha[4];
    if (resc) {
#pragma unroll
      for (int m = 1; m < 16; m <<= 1)
#pragma unroll
        for (int r = 0; r < 4; r++)
          tmax[r] = fmaxf(tmax[r], __shfl_xor(tmax[r], m, 64));
#pragma unroll
      for (int r = 0; r < 4; r++) {
        float mnew = fmaxf(mst[r], tmax[r]);
        alpha[r] = fexp2((mst[r] - mnew) * L2E);
        mst[r] = mnew;
      }
    }

    __syncthreads();   // B1: all waves done reading K(t); drains V(t) loads

    // issue K(t+1); hides under PV
    if (kt + 64 < CHUNK) {
      const int ktB = (kt + 64) * 7680;
#pragma unroll
      for (int j = 0; j < 3; j++)
        if (kact[j]) gload16(kbase + kgo[j] + ktB, Kbuf + koff0 + j * 4096);
    }

    // PV (+ sum column)
    const unsigned short* Vsh = (const unsigned short*)Vbuf;
#pragma unroll
    for (int ks = 0; ks < 2; ks++) {
      bf16x8 pa = *reinterpret_cast<const bf16x8*>(&Psh[w][l15 * 72 + ks * 32 + lq * 8]);
#pragma unroll
      for (int df = 0; df < 5; df++) {
        bf16x8 vb = *reinterpret_cast<const bf16x8*>(&Vsh[(df * 16 + l15) * 72 + ks * 32 + lq * 8]);
        acc[df] = __builtin_amdgcn_mfma_f32_16x16x32_bf16(pa, vb, acc[df], 0, 0, 0);
      }
      acc[5] = __builtin_amdgcn_mfma_f32_16x16x32_bf16(pa, onesb, acc[5], 0, 0, 0);
    }

    // deferred rescale (rare)
    if (resc) {
#pragma unroll
      for (int df = 0; df < 6; df++)
#pragma unroll
        for (int r = 0; r < 4; r++) acc[df][r] *= alpha[r];
    }

    __syncthreads();   // B2: all waves done reading V(t); drains K(t+1) loads

    // issue V(t+1); hides under next tile's QK^T + softmax
    if (kt + 64 < CHUNK) {
      const int ktV = (kt + 64) * 2;
#pragma unroll
      for (int j = 0; j < 3; j++)
        gload16(vbase + vgo[j] + ktV, Vbuf + vw * 1024 + j * 4096);
    }
  }

  // epilogue: out = acc / sum
  unsigned short* obase = outq + (size_t)(ch * CHUNK) * rs + head * HDIM;
  float inv[4];
#pragma unroll
  for (int r = 0; r < 4; r++) inv[r] = 1.0f / __shfl(acc[5][r], lq * 16, 64);
#pragma unroll
  for (int df = 0; df < 5; df++) {
    int col = df * 16 + l15;
#pragma unroll
    for (int r = 0; r < 4; r++) {
      float v = acc[df][r] * inv[r];
      obase[(size_t)(qr0 + lq * 4 + r) * rs + col] = f2bf(v);
    }
  }
}

extern "C" void kernel_launch(void* const* d_in, const int* in_sizes, int n_in,
                              void* d_out, int out_size, void* d_ws, size_t ws_size,
                              hipStream_t stream) {
  const float* hs    = (const float*)d_in[0];   // [8192][1280]
  const float* qkvw  = (const float*)d_in[2];   // [3840][1280]
  const float* qkvb  = (const float*)d_in[3];   // [3840]
  const float* projw = (const float*)d_in[4];   // [1280][1280]
  const float* projb = (const float*)d_in[5];   // [1280]

  char* ws = (char*)d_ws;
  unsigned short* hs_bf    = (unsigned short*)ws;                         // 20,971,520 B
  unsigned short* vT       = hs_bf;                                       // alias (hs_bf dead after QKV gemm)
  unsigned short* qkvw_bf  = (unsigned short*)(ws + 20971520);            //  9,830,400 B
  unsigned short* projw_bf = (unsigned short*)(ws + 20971520 + 9830400);  //  3,276,800 B
  unsigned short* qkv_bf   = (unsigned short*)(ws + 20971520 + 9830400 + 3276800); // 62,914,560 B

  cvt_f32_bf16<<<2048, 256, 0, stream>>>(hs,    hs_bf,    8192 * 1280 / 4);
  cvt_f32_bf16<<<1024, 256, 0, stream>>>(qkvw,  qkvw_bf,  3840 * 1280 / 4);
  cvt_f32_bf16<<<512,  256, 0, stream>>>(projw, projw_bf, 1280 * 1280 / 4);

  // qkv = hs @ qkv_w^T + qkv_b ; q cols pre-scaled (bf16 out)
  gemm_bt<<<dim3(30, 64), 256, 0, stream>>>(hs_bf, qkvw_bf, qkvb, qkv_bf, nullptr,
                                            8192, 3840, 1280, 1280, 1280, QSCALE);
  // one-shot V transpose into hs_bf region (now dead)
  transpose_v<<<dim3(32, 64), 256, 0, stream>>>(qkv_bf, vT);
  // attention; 64 q-rows/block, output overwrites Q-columns of qkv_bf
  attn_kernel<<<dim3(2048), 256, 0, stream>>>(qkv_bf, vT, qkv_bf);
  // out = attn @ proj_w^T + proj_b (fp32 out), A has row stride 3840
  gemm_bt<<<dim3(10, 64), 256, 0, stream>>>(qkv_bf, projw_bf, projb,
                                            nullptr, (float*)d_out,
                                            8192, 1280, 1280, 3840, 0, 1.0f);
}

// Round 13
// 304.535 us; speedup vs baseline: 1.5931x; 1.1424x over previous
//
#include <hip/hip_runtime.h>
#include <hip/hip_bf16.h>
#include <stdint.h>

#define NHEADS 16
#define HDIM 80
#define CHUNK 2048
#define QSCALE 0.11180339887498949f   /* 80^-0.5 */
#define L2E 1.4426950408889634f

typedef __bf16 bf16x8 __attribute__((ext_vector_type(8)));
typedef float f32x4 __attribute__((ext_vector_type(4)));

__device__ __forceinline__ unsigned short f2bf(float f) {
  union { float f; unsigned u; } x; x.f = f;
  unsigned r = (x.u + 0x7fffu + ((x.u >> 16) & 1u)) >> 16;
  return (unsigned short)r;
}

__device__ __forceinline__ float fexp2(float x) {   // raw v_exp_f32
  float r;
  asm("v_exp_f32 %0, %1" : "=v"(r) : "v"(x));
  return r;
}

__device__ __forceinline__ void gload16(const void* g, void* lds) {
  __builtin_amdgcn_global_load_lds((const __attribute__((address_space(1))) void*)g,
                                   (__attribute__((address_space(3))) void*)lds, 16, 0, 0);
}

/* ---------------- fp32 -> bf16 convert ---------------- */
__global__ __launch_bounds__(256) void cvt_f32_bf16(const float* __restrict__ in,
                                                    unsigned short* __restrict__ out, int n4) {
  int i = blockIdx.x * 256 + threadIdx.x;
  int stride = gridDim.x * 256;
  for (; i < n4; i += stride) {
    float4 v = reinterpret_cast<const float4*>(in)[i];
    ushort4 o;
    o.x = f2bf(v.x); o.y = f2bf(v.y); o.z = f2bf(v.z); o.w = f2bf(v.w);
    reinterpret_cast<ushort4*>(out)[i] = o;
  }
}

/* ---------------- bf16 GEMM, BK=64, XOR-swizzled LDS ----------------
   LDS tiles [128][64] bf16, linear (global_load_lds dest must be linear).
   Swizzle (both-sides involution, rule #21): staging source column segment
   seg_g = (lane&7) ^ (lane>>3) (row&7 == lane>>3 for every 1024B chunk);
   fragment reads use seg' = (kk*4+lq) ^ (l15&7). Row stride 128B would be
   a same-bank hotspot; XOR spreads 8 rows over 8 distinct 4-bank windows. */
__global__ __launch_bounds__(256) void gemm_bt(
    const unsigned short* __restrict__ A, const unsigned short* __restrict__ B,
    const float* __restrict__ bias, unsigned short* __restrict__ C,
    float* __restrict__ Cf,
    int M, int N, int K, int lda, int scaleN, float scaleVal)
{
  __shared__ unsigned short Ash[128 * 64];
  __shared__ unsigned short Bsh[128 * 64];
  const int tid = threadIdx.x;
  const int lane = tid & 63;
  const int w = tid >> 6;
  const int wr = w >> 1, wc = w & 1;
  const int l15 = lane & 15, lq = lane >> 4;
  const long bm = (long)blockIdx.y * 128;
  const long bn = (long)blockIdx.x * 128;

  f32x4 acc[4][4];
#pragma unroll
  for (int i = 0; i < 4; i++)
#pragma unroll
    for (int j = 0; j < 4; j++) acc[i][j] = f32x4{0.f, 0.f, 0.f, 0.f};

  const int rlo = lane >> 3;               // row within 8-row chunk (== row&7)
  const int sg  = (lane & 7) ^ rlo;        // pre-swizzled global segment (16B units)

  for (long k0 = 0; k0 < K; k0 += 64) {
    __syncthreads();
#pragma unroll
    for (int j = 0; j < 4; j++) {
      int c = w * 4 + j;                   // chunk 0..15, wave-uniform
      gload16(A + (bm + c * 8 + rlo) * (long)lda + k0 + sg * 8,
              (char*)Ash + c * 1024);
      gload16(B + (bn + c * 8 + rlo) * (long)K + k0 + sg * 8,
              (char*)Bsh + c * 1024);
    }
    __syncthreads();
#pragma unroll
    for (int kk = 0; kk < 2; kk++) {
      const int so = (((kk * 4 + lq) ^ (l15 & 7))) * 8;  // swizzled element offset
      bf16x8 af[4], bfr[4];
#pragma unroll
      for (int x = 0; x < 4; x++) {
        af[x]  = *reinterpret_cast<const bf16x8*>(Ash + (wr * 64 + x * 16 + l15) * 64 + so);
        bfr[x] = *reinterpret_cast<const bf16x8*>(Bsh + (wc * 64 + x * 16 + l15) * 64 + so);
      }
#pragma unroll
      for (int x = 0; x < 4; x++)
#pragma unroll
        for (int y = 0; y < 4; y++)
          acc[x][y] = __builtin_amdgcn_mfma_f32_16x16x32_bf16(af[x], bfr[y], acc[x][y], 0, 0, 0);
    }
  }

#pragma unroll
  for (int x = 0; x < 4; x++) {
    long row0 = bm + wr * 64 + x * 16 + lq * 4;
#pragma unroll
    for (int y = 0; y < 4; y++) {
      int col = (int)bn + wc * 64 + y * 16 + l15;
      float bs = bias[col];
      float sc = (col < scaleN) ? scaleVal : 1.0f;
      if (Cf != nullptr) {
#pragma unroll
        for (int r = 0; r < 4; r++)
          Cf[(size_t)(row0 + r) * N + col] = (acc[x][y][r] + bs) * sc;
      } else {
#pragma unroll
        for (int r = 0; r < 4; r++)
          C[(size_t)(row0 + r) * N + col] = f2bf((acc[x][y][r] + bs) * sc);
      }
    }
  }
}

/* ---------------- one-shot V transpose: qkv V-cols -> vT[chp][80][2048] ---------------- */
__global__ __launch_bounds__(256) void transpose_v(
    const unsigned short* __restrict__ qkv, unsigned short* __restrict__ vt)
{
  __shared__ unsigned short Tsh[64 * 88];
  const int tid = threadIdx.x;
  const int ch = blockIdx.y >> 4, head = blockIdx.y & 15;
  const int st = blockIdx.x;
  const unsigned short* src = qkv + (size_t)(ch * CHUNK + st * 64) * 3840 + 2560 + head * HDIM;
  for (int s = tid; s < 640; s += 256) {
    int r = s / 10, c = s % 10;
    uint4 v = *reinterpret_cast<const uint4*>(src + (size_t)r * 3840 + c * 8);
    *reinterpret_cast<uint4*>(&Tsh[r * 88 + c * 8]) = v;
  }
  __syncthreads();
  unsigned short* dst = vt + ((size_t)(ch * 16 + head) * HDIM) * 2048 + st * 64;
  for (int s = tid; s < 640; s += 256) {
    int d = s >> 3, c2 = s & 7;
    unsigned short ubuf[8];
#pragma unroll
    for (int e = 0; e < 8; e++) ubuf[e] = Tsh[(c2 * 8 + e) * 88 + d];
    *reinterpret_cast<uint4*>(dst + (size_t)d * 2048 + c2 * 8) = *reinterpret_cast<const uint4*>(ubuf);
  }
}

/* ---------------- flash attention (round-10 frozen version) ----------------
   32 q-rows/wave, streaming softmax with post-PV rescale, K/V single-buffered,
   (256,3): best measured config (148 us). Occupancy knob exhausted (rounds
   7/11: (256,4) => forced 64-arch + spill; round 12: QBLK=16 => staging 2x). */
__global__ __launch_bounds__(256, 3) void attn_kernel(
    const unsigned short* __restrict__ qkv, const unsigned short* __restrict__ vt,
    unsigned short* __restrict__ outq)
{
  __shared__ char Kbuf[10240];                  // K tile [64][80], linear
  __shared__ char Vbuf[12288];                  // V tile [80][72]
  __shared__ unsigned short Psh[4][32 * 72];    // per-wave P

  const int tid = threadIdx.x;
  const int lane = tid & 63;
  const int w = tid >> 6;
  const int l15 = lane & 15, lq = lane >> 4;

  // XCD-aware decode: all 16 q-tiles of one (ch,head) land on one XCD
  const int b = blockIdx.x;
  const int qt = (b >> 3) & 15;
  const int chp = (b & 7) * 8 + (b >> 7);   // 0..63 = ch*16+head
  const int ch = chp >> 4;
  const int head = chp & 15;

  const size_t rs = 3840;
  const unsigned short* qbase = qkv + (size_t)(ch * CHUNK) * rs + head * HDIM;
  const char* kbase = (const char*)(qbase + 1280);
  const char* vbase = (const char*)(vt + (size_t)chp * HDIM * 2048);

  // staging geometry: per-lane 32-bit byte offsets (base kept in SGPR)
  int kgo[3]; bool kact[3];
  const int koff0 = w * 1024;
#pragma unroll
  for (int j = 0; j < 3; j++) {
    int c = w + 4 * j;
    kact[j] = (c < 10);
    int cc = kact[j] ? c : 0;
    int s = cc * 64 + lane;
    kgo[j] = (s / 10) * 7680 + (s % 10) * 16;
  }
  int vgo[3];
  const int vw = (w + 2) & 3;
#pragma unroll
  for (int j = 0; j < 3; j++) {
    int c = vw + 4 * j;
    int s2 = c * 64 + lane;
    if (s2 > 719) s2 = 719;
    int d = s2 / 9, u = s2 % 9;
    int ue = (u == 8) ? 0 : u;
    vgo[j] = d * 4096 + ue * 16;
  }

  // Q fragments in registers
  const int qr0 = qt * 128 + w * 32;
  bf16x8 qa[2][2], qa2[2];
#pragma unroll
  for (int qf = 0; qf < 2; qf++) {
    const unsigned short* qrow = qbase + (size_t)(qr0 + qf * 16 + l15) * rs;
    qa[qf][0] = *reinterpret_cast<const bf16x8*>(qrow + lq * 8);
    qa[qf][1] = *reinterpret_cast<const bf16x8*>(qrow + 32 + lq * 8);
    if (lq < 2) qa2[qf] = *reinterpret_cast<const bf16x8*>(qrow + 64 + lq * 8);
    else        qa2[qf] = bf16x8{};
  }

  // ones B-fragment for the sum column
  bf16x8 onesb;
  {
    __bf16 o = (l15 == 0) ? (__bf16)1.0f : (__bf16)0.0f;
    onesb = bf16x8{o, o, o, o, o, o, o, o};
  }

  f32x4 acc[2][6];
#pragma unroll
  for (int qf = 0; qf < 2; qf++)
#pragma unroll
    for (int df = 0; df < 6; df++) acc[qf][df] = f32x4{0.f, 0.f, 0.f, 0.f};
  float mst[2][4];
#pragma unroll
  for (int qf = 0; qf < 2; qf++)
#pragma unroll
    for (int r = 0; r < 4; r++) mst[qf][r] = 16.0f;   // finite upper-bound init

  // prologue: stage K0, V0
#pragma unroll
  for (int j = 0; j < 3; j++)
    if (kact[j]) gload16(kbase + kgo[j], Kbuf + koff0 + j * 4096);
#pragma unroll
  for (int j = 0; j < 3; j++) gload16(vbase + vgo[j], Vbuf + vw * 1024 + j * 4096);
  __syncthreads();

  for (int kt = 0; kt < CHUNK; kt += 64) {
    // QK^T + streaming P (computed with current mst; rescale deferred post-PV)
    float tmax[2][4];
#pragma unroll
    for (int qf = 0; qf < 2; qf++)
#pragma unroll
      for (int r = 0; r < 4; r++) tmax[qf][r] = -1e30f;

    const unsigned short* Ksh = (const unsigned short*)Kbuf;
#pragma unroll
    for (int kf = 0; kf < 4; kf++) {
      const unsigned short* kr = Ksh + (kf * 16 + l15) * 80;
      bf16x8 kb0 = *reinterpret_cast<const bf16x8*>(kr + lq * 8);
      bf16x8 kb1 = *reinterpret_cast<const bf16x8*>(kr + 32 + lq * 8);
      bf16x8 kb2 = (lq < 2) ? *reinterpret_cast<const bf16x8*>(kr + 64 + lq * 8) : bf16x8{};
#pragma unroll
      for (int qf = 0; qf < 2; qf++) {
        f32x4 sv = f32x4{0.f, 0.f, 0.f, 0.f};
        sv = __builtin_amdgcn_mfma_f32_16x16x32_bf16(qa[qf][0], kb0, sv, 0, 0, 0);
        sv = __builtin_amdgcn_mfma_f32_16x16x32_bf16(qa[qf][1], kb1, sv, 0, 0, 0);
        sv = __builtin_amdgcn_mfma_f32_16x16x32_bf16(qa2[qf], kb2, sv, 0, 0, 0);
#pragma unroll
        for (int r = 0; r < 4; r++) {
          tmax[qf][r] = fmaxf(tmax[qf][r], sv[r]);
          float p = fexp2((sv[r] - mst[qf][r]) * L2E);
          unsigned pk;
          asm("v_cvt_pk_bf16_f32 %0, %1, %2" : "=v"(pk) : "v"(p), "v"(p));
          Psh[w][(qf * 16 + lq * 4 + r) * 72 + kf * 16 + l15] = (unsigned short)pk;
        }
      }
    }

    // rescale decision (applied after PV: acc_new = alpha*(acc_old + P*V))
    bool need = false;
#pragma unroll
    for (int qf = 0; qf < 2; qf++)
#pragma unroll
      for (int r = 0; r < 4; r++)
        need = need || (tmax[qf][r] > mst[qf][r] + 8.0f);
    const bool resc = __any(need);
    float alpha[2][4];
    if (resc) {
#pragma unroll
      for (int m = 1; m < 16; m <<= 1)
#pragma unroll
        for (int qf = 0; qf < 2; qf++)
#pragma unroll
          for (int r = 0; r < 4; r++)
            tmax[qf][r] = fmaxf(tmax[qf][r], __shfl_xor(tmax[qf][r], m, 64));
#pragma unroll
      for (int qf = 0; qf < 2; qf++)
#pragma unroll
        for (int r = 0; r < 4; r++) {
          float mnew = fmaxf(mst[qf][r], tmax[qf][r]);
          alpha[qf][r] = fexp2((mst[qf][r] - mnew) * L2E);
          mst[qf][r] = mnew;
        }
    }

    __syncthreads();   // B1: all waves done reading K(t); drains V(t) loads

    // issue K(t+1); hides under PV
    if (kt + 64 < CHUNK) {
      const int ktB = (kt + 64) * 7680;
#pragma unroll
      for (int j = 0; j < 3; j++)
        if (kact[j]) gload16(kbase + kgo[j] + ktB, Kbuf + koff0 + j * 4096);
    }

    // PV (+ sum column)
    const unsigned short* Vsh = (const unsigned short*)Vbuf;
#pragma unroll
    for (int ks = 0; ks < 2; ks++) {
      bf16x8 pa[2];
#pragma unroll
      for (int qf = 0; qf < 2; qf++)
        pa[qf] = *reinterpret_cast<const bf16x8*>(&Psh[w][(qf * 16 + l15) * 72 + ks * 32 + lq * 8]);
#pragma unroll
      for (int df = 0; df < 5; df++) {
        bf16x8 vb = *reinterpret_cast<const bf16x8*>(&Vsh[(df * 16 + l15) * 72 + ks * 32 + lq * 8]);
#pragma unroll
        for (int qf = 0; qf < 2; qf++)
          acc[qf][df] = __builtin_amdgcn_mfma_f32_16x16x32_bf16(pa[qf], vb, acc[qf][df], 0, 0, 0);
      }
#pragma unroll
      for (int qf = 0; qf < 2; qf++)
        acc[qf][5] = __builtin_amdgcn_mfma_f32_16x16x32_bf16(pa[qf], onesb, acc[qf][5], 0, 0, 0);
    }

    // deferred rescale (rare)
    if (resc) {
#pragma unroll
      for (int qf = 0; qf < 2; qf++)
#pragma unroll
        for (int df = 0; df < 6; df++)
#pragma unroll
          for (int r = 0; r < 4; r++) acc[qf][df][r] *= alpha[qf][r];
    }

    __syncthreads();   // B2: all waves done reading V(t); drains K(t+1) loads

    // issue V(t+1); hides under next tile's QK^T + softmax
    if (kt + 64 < CHUNK) {
      const int ktV = (kt + 64) * 2;
#pragma unroll
      for (int j = 0; j < 3; j++)
        gload16(vbase + vgo[j] + ktV, Vbuf + vw * 1024 + j * 4096);
    }
  }

  // epilogue: out = acc / sum
  unsigned short* obase = outq + (size_t)(ch * CHUNK) * rs + head * HDIM;
#pragma unroll
  for (int qf = 0; qf < 2; qf++) {
    float inv[4];
#pragma unroll
    for (int r = 0; r < 4; r++) inv[r] = 1.0f / __shfl(acc[qf][5][r], lq * 16, 64);
#pragma unroll
    for (int df = 0; df < 5; df++) {
      int col = df * 16 + l15;
#pragma unroll
      for (int r = 0; r < 4; r++) {
        float v = acc[qf][df][r] * inv[r];
        obase[(size_t)(qr0 + qf * 16 + lq * 4 + r) * rs + col] = f2bf(v);
      }
    }
  }
}

extern "C" void kernel_launch(void* const* d_in, const int* in_sizes, int n_in,
                              void* d_out, int out_size, void* d_ws, size_t ws_size,
                              hipStream_t stream) {
  const float* hs    = (const float*)d_in[0];   // [8192][1280]
  const float* qkvw  = (const float*)d_in[2];   // [3840][1280]
  const float* qkvb  = (const float*)d_in[3];   // [3840]
  const float* projw = (const float*)d_in[4];   // [1280][1280]
  const float* projb = (const float*)d_in[5];   // [1280]

  char* ws = (char*)d_ws;
  unsigned short* hs_bf    = (unsigned short*)ws;                         // 20,971,520 B
  unsigned short* vT       = hs_bf;                                       // alias (hs_bf dead after QKV gemm)
  unsigned short* qkvw_bf  = (unsigned short*)(ws + 20971520);            //  9,830,400 B
  unsigned short* projw_bf = (unsigned short*)(ws + 20971520 + 9830400);  //  3,276,800 B
  unsigned short* qkv_bf   = (unsigned short*)(ws + 20971520 + 9830400 + 3276800); // 62,914,560 B

  cvt_f32_bf16<<<2048, 256, 0, stream>>>(hs,    hs_bf,    8192 * 1280 / 4);
  cvt_f32_bf16<<<1024, 256, 0, stream>>>(qkvw,  qkvw_bf,  3840 * 1280 / 4);
  cvt_f32_bf16<<<512,  256, 0, stream>>>(projw, projw_bf, 1280 * 1280 / 4);

  // qkv = hs @ qkv_w^T + qkv_b ; q cols pre-scaled (bf16 out)
  gemm_bt<<<dim3(30, 64), 256, 0, stream>>>(hs_bf, qkvw_bf, qkvb, qkv_bf, nullptr,
                                            8192, 3840, 1280, 1280, 1280, QSCALE);
  // one-shot V transpose into hs_bf region (now dead)
  transpose_v<<<dim3(32, 64), 256, 0, stream>>>(qkv_bf, vT);
  // attention; output overwrites Q-columns of qkv_bf (XCD-swizzled 1-D grid)
  attn_kernel<<<dim3(1024), 256, 0, stream>>>(qkv_bf, vT, qkv_bf);
  // out = attn @ proj_w^T + proj_b (fp32 out), A has row stride 3840
  gemm_bt<<<dim3(10, 64), 256, 0, stream>>>(qkv_bf, projw_bf, projb,
                                            nullptr, (float*)d_out,
                                            8192, 1280, 1280, 3840, 0, 1.0f);
}

// Round 14
// 302.361 us; speedup vs baseline: 1.6046x; 1.0072x over previous
//
#include <hip/hip_runtime.h>
#include <hip/hip_bf16.h>
#include <stdint.h>

#define NHEADS 16
#define HDIM 80
#define CHUNK 2048
#define QSCALE 0.11180339887498949f   /* 80^-0.5 */
#define L2E 1.4426950408889634f

typedef __bf16 bf16x8 __attribute__((ext_vector_type(8)));
typedef float f32x4 __attribute__((ext_vector_type(4)));

__device__ __forceinline__ unsigned short f2bf(float f) {
  union { float f; unsigned u; } x; x.f = f;
  unsigned r = (x.u + 0x7fffu + ((x.u >> 16) & 1u)) >> 16;
  return (unsigned short)r;
}

__device__ __forceinline__ float fexp2(float x) {   // raw v_exp_f32
  float r;
  asm("v_exp_f32 %0, %1" : "=v"(r) : "v"(x));
  return r;
}

__device__ __forceinline__ void gload16(const void* g, void* lds) {
  __builtin_amdgcn_global_load_lds((const __attribute__((address_space(1))) void*)g,
                                   (__attribute__((address_space(3))) void*)lds, 16, 0, 0);
}

/* ---------------- fp32 -> bf16 convert ---------------- */
__global__ __launch_bounds__(256) void cvt_f32_bf16(const float* __restrict__ in,
                                                    unsigned short* __restrict__ out, int n4) {
  int i = blockIdx.x * 256 + threadIdx.x;
  int stride = gridDim.x * 256;
  for (; i < n4; i += stride) {
    float4 v = reinterpret_cast<const float4*>(in)[i];
    ushort4 o;
    o.x = f2bf(v.x); o.y = f2bf(v.y); o.z = f2bf(v.z); o.w = f2bf(v.w);
    reinterpret_cast<ushort4*>(out)[i] = o;
  }
}

/* ---------------- bf16 GEMM, BK=64, XOR-swizzled LDS (round-13 proven) ---------------- */
__global__ __launch_bounds__(256) void gemm_bt(
    const unsigned short* __restrict__ A, const unsigned short* __restrict__ B,
    const float* __restrict__ bias, unsigned short* __restrict__ C,
    float* __restrict__ Cf,
    int M, int N, int K, int lda, int scaleN, float scaleVal)
{
  __shared__ unsigned short Ash[128 * 64];
  __shared__ unsigned short Bsh[128 * 64];
  const int tid = threadIdx.x;
  const int lane = tid & 63;
  const int w = tid >> 6;
  const int wr = w >> 1, wc = w & 1;
  const int l15 = lane & 15, lq = lane >> 4;
  const long bm = (long)blockIdx.y * 128;
  const long bn = (long)blockIdx.x * 128;

  f32x4 acc[4][4];
#pragma unroll
  for (int i = 0; i < 4; i++)
#pragma unroll
    for (int j = 0; j < 4; j++) acc[i][j] = f32x4{0.f, 0.f, 0.f, 0.f};

  const int rlo = lane >> 3;               // row within 8-row chunk (== row&7)
  const int sg  = (lane & 7) ^ rlo;        // pre-swizzled global segment (16B units)

  for (long k0 = 0; k0 < K; k0 += 64) {
    __syncthreads();
#pragma unroll
    for (int j = 0; j < 4; j++) {
      int c = w * 4 + j;                   // chunk 0..15, wave-uniform
      gload16(A + (bm + c * 8 + rlo) * (long)lda + k0 + sg * 8,
              (char*)Ash + c * 1024);
      gload16(B + (bn + c * 8 + rlo) * (long)K + k0 + sg * 8,
              (char*)Bsh + c * 1024);
    }
    __syncthreads();
#pragma unroll
    for (int kk = 0; kk < 2; kk++) {
      const int so = (((kk * 4 + lq) ^ (l15 & 7))) * 8;  // swizzled element offset
      bf16x8 af[4], bfr[4];
#pragma unroll
      for (int x = 0; x < 4; x++) {
        af[x]  = *reinterpret_cast<const bf16x8*>(Ash + (wr * 64 + x * 16 + l15) * 64 + so);
        bfr[x] = *reinterpret_cast<const bf16x8*>(Bsh + (wc * 64 + x * 16 + l15) * 64 + so);
      }
#pragma unroll
      for (int x = 0; x < 4; x++)
#pragma unroll
        for (int y = 0; y < 4; y++)
          acc[x][y] = __builtin_amdgcn_mfma_f32_16x16x32_bf16(af[x], bfr[y], acc[x][y], 0, 0, 0);
    }
  }

#pragma unroll
  for (int x = 0; x < 4; x++) {
    long row0 = bm + wr * 64 + x * 16 + lq * 4;
#pragma unroll
    for (int y = 0; y < 4; y++) {
      int col = (int)bn + wc * 64 + y * 16 + l15;
      float bs = bias[col];
      float sc = (col < scaleN) ? scaleVal : 1.0f;
      if (Cf != nullptr) {
#pragma unroll
        for (int r = 0; r < 4; r++)
          Cf[(size_t)(row0 + r) * N + col] = (acc[x][y][r] + bs) * sc;
      } else {
#pragma unroll
        for (int r = 0; r < 4; r++)
          C[(size_t)(row0 + r) * N + col] = f2bf((acc[x][y][r] + bs) * sc);
      }
    }
  }
}

/* ---------------- one-shot V transpose: qkv V-cols -> vT[chp][80][2048] ---------------- */
__global__ __launch_bounds__(256) void transpose_v(
    const unsigned short* __restrict__ qkv, unsigned short* __restrict__ vt)
{
  __shared__ unsigned short Tsh[64 * 88];
  const int tid = threadIdx.x;
  const int ch = blockIdx.y >> 4, head = blockIdx.y & 15;
  const int st = blockIdx.x;
  const unsigned short* src = qkv + (size_t)(ch * CHUNK + st * 64) * 3840 + 2560 + head * HDIM;
  for (int s = tid; s < 640; s += 256) {
    int r = s / 10, c = s % 10;
    uint4 v = *reinterpret_cast<const uint4*>(src + (size_t)r * 3840 + c * 8);
    *reinterpret_cast<uint4*>(&Tsh[r * 88 + c * 8]) = v;
  }
  __syncthreads();
  unsigned short* dst = vt + ((size_t)(ch * 16 + head) * HDIM) * 2048 + st * 64;
  for (int s = tid; s < 640; s += 256) {
    int d = s >> 3, c2 = s & 7;
    unsigned short ubuf[8];
#pragma unroll
    for (int e = 0; e < 8; e++) ubuf[e] = Tsh[(c2 * 8 + e) * 88 + d];
    *reinterpret_cast<uint4*>(dst + (size_t)d * 2048 + c2 * 8) = *reinterpret_cast<const uint4*>(ubuf);
  }
}

/* ---------------- flash attention, KVBLK=128 ----------------
   Halves per-key fixed costs (barriers 64->32, rescale checks, loop overhead)
   vs the 64-key version; MFMA/VALU per key unchanged. LDS 77824 B -> 2
   blocks/CU, which the register file (132 total regs > 128-granule) already
   binds to: zero occupancy cost. Same proven single-buffer prefetch timing:
   K(t+1) after B1 (hides under PV), V(t+1) after B2 (hides under QK+softmax). */
__global__ __launch_bounds__(256, 3) void attn_kernel(
    const unsigned short* __restrict__ qkv, const unsigned short* __restrict__ vt,
    unsigned short* __restrict__ outq)
{
  __shared__ char Kbuf[20480];                  // K tile [128][80], linear, 20 chunks
  __shared__ char Vbuf[22528];                  // V tile [80][136] padded, 22 chunks
  __shared__ unsigned short Psh[4][4352];       // per-wave P [32][136]

  const int tid = threadIdx.x;
  const int lane = tid & 63;
  const int w = tid >> 6;
  const int l15 = lane & 15, lq = lane >> 4;

  // XCD-aware decode: all 16 q-tiles of one (ch,head) land on one XCD
  const int b = blockIdx.x;
  const int qt = (b >> 3) & 15;
  const int chp = (b & 7) * 8 + (b >> 7);   // 0..63 = ch*16+head
  const int ch = chp >> 4;
  const int head = chp & 15;

  const size_t rs = 3840;
  const unsigned short* qbase = qkv + (size_t)(ch * CHUNK) * rs + head * HDIM;
  const char* kbase = (const char*)(qbase + 1280);
  const char* vbase = (const char*)(vt + (size_t)chp * HDIM * 2048);

  // --- K staging: 20 chunks of 1024B; wave w owns c = w+4j, j<5 (all real) ---
  int kgo[5];
#pragma unroll
  for (int j = 0; j < 5; j++) {
    int X = (w + 4 * j) * 1024 + lane * 16;
    kgo[j] = (X / 160) * 7680 + (X % 160);     // row*rowstride + seg*16
  }
  // --- V staging: 22 chunks; wave w owns c = w+4j, j<6, real if c<22 ---
  int vgo[6]; bool vact[6];
#pragma unroll
  for (int j = 0; j < 6; j++) {
    int c = w + 4 * j;
    vact[j] = (c < 22);
    int cc = vact[j] ? c : 0;
    int X = cc * 1024 + lane * 16;
    int row = X / 272, seg = (X % 272) / 16;   // 272B padded rows (17 segs)
    if (seg >= 16 || row >= 80) { row = 0; seg = 0; }   // pad slot: safe src
    vgo[j] = row * 4096 + seg * 16;
  }

  // Q fragments in registers
  const int qr0 = qt * 128 + w * 32;
  bf16x8 qa[2][2], qa2[2];
#pragma unroll
  for (int qf = 0; qf < 2; qf++) {
    const unsigned short* qrow = qbase + (size_t)(qr0 + qf * 16 + l15) * rs;
    qa[qf][0] = *reinterpret_cast<const bf16x8*>(qrow + lq * 8);
    qa[qf][1] = *reinterpret_cast<const bf16x8*>(qrow + 32 + lq * 8);
    if (lq < 2) qa2[qf] = *reinterpret_cast<const bf16x8*>(qrow + 64 + lq * 8);
    else        qa2[qf] = bf16x8{};
  }

  // ones B-fragment for the sum column
  bf16x8 onesb;
  {
    __bf16 o = (l15 == 0) ? (__bf16)1.0f : (__bf16)0.0f;
    onesb = bf16x8{o, o, o, o, o, o, o, o};
  }

  f32x4 acc[2][6];
#pragma unroll
  for (int qf = 0; qf < 2; qf++)
#pragma unroll
    for (int df = 0; df < 6; df++) acc[qf][df] = f32x4{0.f, 0.f, 0.f, 0.f};
  float mst[2][4], msl[2][4];
#pragma unroll
  for (int qf = 0; qf < 2; qf++)
#pragma unroll
    for (int r = 0; r < 4; r++) { mst[qf][r] = 16.0f; msl[qf][r] = 16.0f * L2E; }

  // prologue: stage K0, V0
#pragma unroll
  for (int j = 0; j < 5; j++) gload16(kbase + kgo[j], Kbuf + (w + 4 * j) * 1024);
#pragma unroll
  for (int j = 0; j < 6; j++)
    if (vact[j]) gload16(vbase + vgo[j], Vbuf + (w + 4 * j) * 1024);
  __syncthreads();

  for (int kt = 0; kt < CHUNK; kt += 128) {
    // QK^T + streaming P (with current mst; rescale deferred post-PV)
    float tmax[2][4];
#pragma unroll
    for (int qf = 0; qf < 2; qf++)
#pragma unroll
      for (int r = 0; r < 4; r++) tmax[qf][r] = -1e30f;

    const unsigned short* Ksh = (const unsigned short*)Kbuf;
#pragma unroll
    for (int kf = 0; kf < 8; kf++) {
      const unsigned short* kr = Ksh + (kf * 16 + l15) * 80;
      bf16x8 kb0 = *reinterpret_cast<const bf16x8*>(kr + lq * 8);
      bf16x8 kb1 = *reinterpret_cast<const bf16x8*>(kr + 32 + lq * 8);
      bf16x8 kb2 = (lq < 2) ? *reinterpret_cast<const bf16x8*>(kr + 64 + lq * 8) : bf16x8{};
#pragma unroll
      for (int qf = 0; qf < 2; qf++) {
        f32x4 sv = f32x4{0.f, 0.f, 0.f, 0.f};
        sv = __builtin_amdgcn_mfma_f32_16x16x32_bf16(qa[qf][0], kb0, sv, 0, 0, 0);
        sv = __builtin_amdgcn_mfma_f32_16x16x32_bf16(qa[qf][1], kb1, sv, 0, 0, 0);
        sv = __builtin_amdgcn_mfma_f32_16x16x32_bf16(qa2[qf], kb2, sv, 0, 0, 0);
#pragma unroll
        for (int r = 0; r < 4; r++) {
          tmax[qf][r] = fmaxf(tmax[qf][r], sv[r]);
          float p = fexp2(fmaf(sv[r], L2E, -msl[qf][r]));
          unsigned pk;
          asm("v_cvt_pk_bf16_f32 %0, %1, %2" : "=v"(pk) : "v"(p), "v"(p));
          Psh[w][(qf * 16 + lq * 4 + r) * 136 + kf * 16 + l15] = (unsigned short)pk;
        }
      }
    }

    // rescale decision (applied after PV: acc_new = alpha*(acc_old + P*V))
    bool need = false;
#pragma unroll
    for (int qf = 0; qf < 2; qf++)
#pragma unroll
      for (int r = 0; r < 4; r++)
        need = need || (tmax[qf][r] > mst[qf][r] + 8.0f);
    const bool resc = __any(need);
    float alpha[2][4];
    if (resc) {
#pragma unroll
      for (int m = 1; m < 16; m <<= 1)
#pragma unroll
        for (int qf = 0; qf < 2; qf++)
#pragma unroll
          for (int r = 0; r < 4; r++)
            tmax[qf][r] = fmaxf(tmax[qf][r], __shfl_xor(tmax[qf][r], m, 64));
#pragma unroll
      for (int qf = 0; qf < 2; qf++)
#pragma unroll
        for (int r = 0; r < 4; r++) {
          float mnew = fmaxf(mst[qf][r], tmax[qf][r]);
          alpha[qf][r] = fexp2((mst[qf][r] - mnew) * L2E);
          mst[qf][r] = mnew;
          msl[qf][r] = mnew * L2E;
        }
    }

    __syncthreads();   // B1: all waves done reading K(t); drains V(t) loads

    // issue K(t+1); hides under PV
    if (kt + 128 < CHUNK) {
      const int ktB = (kt + 128) * 7680;
#pragma unroll
      for (int j = 0; j < 5; j++)
        gload16(kbase + kgo[j] + ktB, Kbuf + (w + 4 * j) * 1024);
    }

    // PV (+ sum column)
    const unsigned short* Vsh = (const unsigned short*)Vbuf;
#pragma unroll
    for (int ks = 0; ks < 4; ks++) {
      bf16x8 pa[2];
#pragma unroll
      for (int qf = 0; qf < 2; qf++)
        pa[qf] = *reinterpret_cast<const bf16x8*>(&Psh[w][(qf * 16 + l15) * 136 + ks * 32 + lq * 8]);
#pragma unroll
      for (int df = 0; df < 5; df++) {
        bf16x8 vb = *reinterpret_cast<const bf16x8*>(&Vsh[(df * 16 + l15) * 136 + ks * 32 + lq * 8]);
#pragma unroll
        for (int qf = 0; qf < 2; qf++)
          acc[qf][df] = __builtin_amdgcn_mfma_f32_16x16x32_bf16(pa[qf], vb, acc[qf][df], 0, 0, 0);
      }
#pragma unroll
      for (int qf = 0; qf < 2; qf++)
        acc[qf][5] = __builtin_amdgcn_mfma_f32_16x16x32_bf16(pa[qf], onesb, acc[qf][5], 0, 0, 0);
    }

    // deferred rescale (rare)
    if (resc) {
#pragma unroll
      for (int qf = 0; qf < 2; qf++)
#pragma unroll
        for (int df = 0; df < 6; df++)
#pragma unroll
          for (int r = 0; r < 4; r++) acc[qf][df][r] *= alpha[qf][r];
    }

    __syncthreads();   // B2: all waves done reading V(t); drains K(t+1) loads

    // issue V(t+1); hides under next tile's QK^T + softmax
    if (kt + 128 < CHUNK) {
      const int ktV = (kt + 128) * 2;
#pragma unroll
      for (int j = 0; j < 6; j++)
        if (vact[j]) gload16(vbase + vgo[j] + ktV, Vbuf + (w + 4 * j) * 1024);
    }
  }

  // epilogue: out = acc / sum
  unsigned short* obase = outq + (size_t)(ch * CHUNK) * rs + head * HDIM;
#pragma unroll
  for (int qf = 0; qf < 2; qf++) {
    float inv[4];
#pragma unroll
    for (int r = 0; r < 4; r++) inv[r] = 1.0f / __shfl(acc[qf][5][r], lq * 16, 64);
#pragma unroll
    for (int df = 0; df < 5; df++) {
      int col = df * 16 + l15;
#pragma unroll
      for (int r = 0; r < 4; r++) {
        float v = acc[qf][df][r] * inv[r];
        obase[(size_t)(qr0 + qf * 16 + lq * 4 + r) * rs + col] = f2bf(v);
      }
    }
  }
}

extern "C" void kernel_launch(void* const* d_in, const int* in_sizes, int n_in,
                              void* d_out, int out_size, void* d_ws, size_t ws_size,
                              hipStream_t stream) {
  const float* hs    = (const float*)d_in[0];   // [8192][1280]
  const float* qkvw  = (const float*)d_in[2];   // [3840][1280]
  const float* qkvb  = (const float*)d_in[3];   // [3840]
  const float* projw = (const float*)d_in[4];   // [1280][1280]
  const float* projb = (const float*)d_in[5];   // [1280]

  char* ws = (char*)d_ws;
  unsigned short* hs_bf    = (unsigned short*)ws;                         // 20,971,520 B
  unsigned short* vT       = hs_bf;                                       // alias (hs_bf dead after QKV gemm)
  unsigned short* qkvw_bf  = (unsigned short*)(ws + 20971520);            //  9,830,400 B
  unsigned short* projw_bf = (unsigned short*)(ws + 20971520 + 9830400);  //  3,276,800 B
  unsigned short* qkv_bf   = (unsigned short*)(ws + 20971520 + 9830400 + 3276800); // 62,914,560 B

  cvt_f32_bf16<<<2048, 256, 0, stream>>>(hs,    hs_bf,    8192 * 1280 / 4);
  cvt_f32_bf16<<<1024, 256, 0, stream>>>(qkvw,  qkvw_bf,  3840 * 1280 / 4);
  cvt_f32_bf16<<<512,  256, 0, stream>>>(projw, projw_bf, 1280 * 1280 / 4);

  // qkv = hs @ qkv_w^T + qkv_b ; q cols pre-scaled (bf16 out)
  gemm_bt<<<dim3(30, 64), 256, 0, stream>>>(hs_bf, qkvw_bf, qkvb, qkv_bf, nullptr,
                                            8192, 3840, 1280, 1280, 1280, QSCALE);
  // one-shot V transpose into hs_bf region (now dead)
  transpose_v<<<dim3(32, 64), 256, 0, stream>>>(qkv_bf, vT);
  // attention; output overwrites Q-columns of qkv_bf (XCD-swizzled 1-D grid)
  attn_kernel<<<dim3(1024), 256, 0, stream>>>(qkv_bf, vT, qkv_bf);
  // out = attn @ proj_w^T + proj_b (fp32 out), A has row stride 3840
  gemm_bt<<<dim3(10, 64), 256, 0, stream>>>(qkv_bf, projw_bf, projb,
                                            nullptr, (float*)d_out,
                                            8192, 1280, 1280, 3840, 0, 1.0f);
}

// Round 15
// 298.424 us; speedup vs baseline: 1.6258x; 1.0132x over previous
//
#include <hip/hip_runtime.h>
#include <hip/hip_bf16.h>
#include <stdint.h>

#define NHEADS 16
#define HDIM 80
#define CHUNK 2048
#define QSCALE 0.11180339887498949f   /* 80^-0.5 */
#define L2E 1.4426950408889634f

typedef __bf16 bf16x8 __attribute__((ext_vector_type(8)));
typedef float f32x4 __attribute__((ext_vector_type(4)));

__device__ __forceinline__ unsigned short f2bf(float f) {
  union { float f; unsigned u; } x; x.f = f;
  unsigned r = (x.u + 0x7fffu + ((x.u >> 16) & 1u)) >> 16;
  return (unsigned short)r;
}

__device__ __forceinline__ float fexp2(float x) {   // raw v_exp_f32
  float r;
  asm("v_exp_f32 %0, %1" : "=v"(r) : "v"(x));
  return r;
}

__device__ __forceinline__ void gload16(const void* g, void* lds) {
  __builtin_amdgcn_global_load_lds((const __attribute__((address_space(1))) void*)g,
                                   (__attribute__((address_space(3))) void*)lds, 16, 0, 0);
}

/* ---------------- fp32 -> bf16 convert ---------------- */
__global__ __launch_bounds__(256) void cvt_f32_bf16(const float* __restrict__ in,
                                                    unsigned short* __restrict__ out, int n4) {
  int i = blockIdx.x * 256 + threadIdx.x;
  int stride = gridDim.x * 256;
  for (; i < n4; i += stride) {
    float4 v = reinterpret_cast<const float4*>(in)[i];
    ushort4 o;
    o.x = f2bf(v.x); o.y = f2bf(v.y); o.z = f2bf(v.z); o.w = f2bf(v.w);
    reinterpret_cast<ushort4*>(out)[i] = o;
  }
}

/* ---------------- bf16 GEMM, BK=64, XOR-swizzled LDS (round-13 proven) ----------------
   Fused V-transpose epilogue: when vt != nullptr, columns >= 2560 (the V part
   of the QKV output) are written TRANSPOSED to vt[chp][80][2048] instead of C.
   Each thread's 4 acc rows are 4 contiguous seq elements -> one ushort4 store.
   The 2560 boundary is 128-aligned, so the branch is wave-uniform per y-frag. */
__global__ __launch_bounds__(256) void gemm_bt(
    const unsigned short* __restrict__ A, const unsigned short* __restrict__ B,
    const float* __restrict__ bias, unsigned short* __restrict__ C,
    float* __restrict__ Cf, unsigned short* __restrict__ vt,
    int M, int N, int K, int lda, int scaleN, float scaleVal)
{
  __shared__ unsigned short Ash[128 * 64];
  __shared__ unsigned short Bsh[128 * 64];
  const int tid = threadIdx.x;
  const int lane = tid & 63;
  const int w = tid >> 6;
  const int wr = w >> 1, wc = w & 1;
  const int l15 = lane & 15, lq = lane >> 4;
  const long bm = (long)blockIdx.y * 128;
  const long bn = (long)blockIdx.x * 128;

  f32x4 acc[4][4];
#pragma unroll
  for (int i = 0; i < 4; i++)
#pragma unroll
    for (int j = 0; j < 4; j++) acc[i][j] = f32x4{0.f, 0.f, 0.f, 0.f};

  const int rlo = lane >> 3;               // row within 8-row chunk (== row&7)
  const int sg  = (lane & 7) ^ rlo;        // pre-swizzled global segment (16B units)

  for (long k0 = 0; k0 < K; k0 += 64) {
    __syncthreads();
#pragma unroll
    for (int j = 0; j < 4; j++) {
      int c = w * 4 + j;                   // chunk 0..15, wave-uniform
      gload16(A + (bm + c * 8 + rlo) * (long)lda + k0 + sg * 8,
              (char*)Ash + c * 1024);
      gload16(B + (bn + c * 8 + rlo) * (long)K + k0 + sg * 8,
              (char*)Bsh + c * 1024);
    }
    __syncthreads();
#pragma unroll
    for (int kk = 0; kk < 2; kk++) {
      const int so = (((kk * 4 + lq) ^ (l15 & 7))) * 8;  // swizzled element offset
      bf16x8 af[4], bfr[4];
#pragma unroll
      for (int x = 0; x < 4; x++) {
        af[x]  = *reinterpret_cast<const bf16x8*>(Ash + (wr * 64 + x * 16 + l15) * 64 + so);
        bfr[x] = *reinterpret_cast<const bf16x8*>(Bsh + (wc * 64 + x * 16 + l15) * 64 + so);
      }
#pragma unroll
      for (int x = 0; x < 4; x++)
#pragma unroll
        for (int y = 0; y < 4; y++)
          acc[x][y] = __builtin_amdgcn_mfma_f32_16x16x32_bf16(af[x], bfr[y], acc[x][y], 0, 0, 0);
    }
  }

#pragma unroll
  for (int x = 0; x < 4; x++) {
    long row0 = bm + wr * 64 + x * 16 + lq * 4;
#pragma unroll
    for (int y = 0; y < 4; y++) {
      int colu = (int)bn + wc * 64 + y * 16;   // wave-uniform column base
      int col = colu + l15;
      float bs = bias[col];
      if (vt != nullptr && colu >= 2560) {
        // V part: write transposed to vt[chp][80][2048]
        int vcol = col - 2560;
        int vh = vcol / 80, vd = vcol % 80;
        int chp = ((int)(row0 >> 11)) * 16 + vh;
        int seq = (int)row0 & 2047;
        ushort4 o;
        o.x = f2bf(acc[x][y][0] + bs);
        o.y = f2bf(acc[x][y][1] + bs);
        o.z = f2bf(acc[x][y][2] + bs);
        o.w = f2bf(acc[x][y][3] + bs);
        *reinterpret_cast<ushort4*>(vt + ((size_t)chp * 80 + vd) * 2048 + seq) = o;
      } else {
        float sc = (col < scaleN) ? scaleVal : 1.0f;
        if (Cf != nullptr) {
#pragma unroll
          for (int r = 0; r < 4; r++)
            Cf[(size_t)(row0 + r) * N + col] = (acc[x][y][r] + bs) * sc;
        } else {
#pragma unroll
          for (int r = 0; r < 4; r++)
            C[(size_t)(row0 + r) * N + col] = f2bf((acc[x][y][r] + bs) * sc);
        }
      }
    }
  }
}

/* ---------------- flash attention (round-13 measured-best, byte-identical) ----------------
   32 q-rows/wave, streaming softmax with post-PV rescale, K/V single-buffered,
   (256,3), KVBLK=64. 149.1 us measured. Occupancy knob exhausted (rounds 7/11:
   (256,4) => forced 64-arch + spill; round 12: QBLK=16 => staging 2x; round 14:
   KVBLK=128 => no gain). */
__global__ __launch_bounds__(256, 3) void attn_kernel(
    const unsigned short* __restrict__ qkv, const unsigned short* __restrict__ vt,
    unsigned short* __restrict__ outq)
{
  __shared__ char Kbuf[10240];                  // K tile [64][80], linear
  __shared__ char Vbuf[12288];                  // V tile [80][72]
  __shared__ unsigned short Psh[4][32 * 72];    // per-wave P

  const int tid = threadIdx.x;
  const int lane = tid & 63;
  const int w = tid >> 6;
  const int l15 = lane & 15, lq = lane >> 4;

  // XCD-aware decode: all 16 q-tiles of one (ch,head) land on one XCD
  const int b = blockIdx.x;
  const int qt = (b >> 3) & 15;
  const int chp = (b & 7) * 8 + (b >> 7);   // 0..63 = ch*16+head
  const int ch = chp >> 4;
  const int head = chp & 15;

  const size_t rs = 3840;
  const unsigned short* qbase = qkv + (size_t)(ch * CHUNK) * rs + head * HDIM;
  const char* kbase = (const char*)(qbase + 1280);
  const char* vbase = (const char*)(vt + (size_t)chp * HDIM * 2048);

  // staging geometry: per-lane 32-bit byte offsets (base kept in SGPR)
  int kgo[3]; bool kact[3];
  const int koff0 = w * 1024;
#pragma unroll
  for (int j = 0; j < 3; j++) {
    int c = w + 4 * j;
    kact[j] = (c < 10);
    int cc = kact[j] ? c : 0;
    int s = cc * 64 + lane;
    kgo[j] = (s / 10) * 7680 + (s % 10) * 16;
  }
  int vgo[3];
  const int vw = (w + 2) & 3;
#pragma unroll
  for (int j = 0; j < 3; j++) {
    int c = vw + 4 * j;
    int s2 = c * 64 + lane;
    if (s2 > 719) s2 = 719;
    int d = s2 / 9, u = s2 % 9;
    int ue = (u == 8) ? 0 : u;
    vgo[j] = d * 4096 + ue * 16;
  }

  // Q fragments in registers
  const int qr0 = qt * 128 + w * 32;
  bf16x8 qa[2][2], qa2[2];
#pragma unroll
  for (int qf = 0; qf < 2; qf++) {
    const unsigned short* qrow = qbase + (size_t)(qr0 + qf * 16 + l15) * rs;
    qa[qf][0] = *reinterpret_cast<const bf16x8*>(qrow + lq * 8);
    qa[qf][1] = *reinterpret_cast<const bf16x8*>(qrow + 32 + lq * 8);
    if (lq < 2) qa2[qf] = *reinterpret_cast<const bf16x8*>(qrow + 64 + lq * 8);
    else        qa2[qf] = bf16x8{};
  }

  // ones B-fragment for the sum column
  bf16x8 onesb;
  {
    __bf16 o = (l15 == 0) ? (__bf16)1.0f : (__bf16)0.0f;
    onesb = bf16x8{o, o, o, o, o, o, o, o};
  }

  f32x4 acc[2][6];
#pragma unroll
  for (int qf = 0; qf < 2; qf++)
#pragma unroll
    for (int df = 0; df < 6; df++) acc[qf][df] = f32x4{0.f, 0.f, 0.f, 0.f};
  float mst[2][4];
#pragma unroll
  for (int qf = 0; qf < 2; qf++)
#pragma unroll
    for (int r = 0; r < 4; r++) mst[qf][r] = 16.0f;   // finite upper-bound init

  // prologue: stage K0, V0
#pragma unroll
  for (int j = 0; j < 3; j++)
    if (kact[j]) gload16(kbase + kgo[j], Kbuf + koff0 + j * 4096);
#pragma unroll
  for (int j = 0; j < 3; j++) gload16(vbase + vgo[j], Vbuf + vw * 1024 + j * 4096);
  __syncthreads();

  for (int kt = 0; kt < CHUNK; kt += 64) {
    // QK^T + streaming P (computed with current mst; rescale deferred post-PV)
    float tmax[2][4];
#pragma unroll
    for (int qf = 0; qf < 2; qf++)
#pragma unroll
      for (int r = 0; r < 4; r++) tmax[qf][r] = -1e30f;

    const unsigned short* Ksh = (const unsigned short*)Kbuf;
#pragma unroll
    for (int kf = 0; kf < 4; kf++) {
      const unsigned short* kr = Ksh + (kf * 16 + l15) * 80;
      bf16x8 kb0 = *reinterpret_cast<const bf16x8*>(kr + lq * 8);
      bf16x8 kb1 = *reinterpret_cast<const bf16x8*>(kr + 32 + lq * 8);
      bf16x8 kb2 = (lq < 2) ? *reinterpret_cast<const bf16x8*>(kr + 64 + lq * 8) : bf16x8{};
#pragma unroll
      for (int qf = 0; qf < 2; qf++) {
        f32x4 sv = f32x4{0.f, 0.f, 0.f, 0.f};
        sv = __builtin_amdgcn_mfma_f32_16x16x32_bf16(qa[qf][0], kb0, sv, 0, 0, 0);
        sv = __builtin_amdgcn_mfma_f32_16x16x32_bf16(qa[qf][1], kb1, sv, 0, 0, 0);
        sv = __builtin_amdgcn_mfma_f32_16x16x32_bf16(qa2[qf], kb2, sv, 0, 0, 0);
#pragma unroll
        for (int r = 0; r < 4; r++) {
          tmax[qf][r] = fmaxf(tmax[qf][r], sv[r]);
          float p = fexp2((sv[r] - mst[qf][r]) * L2E);
          unsigned pk;
          asm("v_cvt_pk_bf16_f32 %0, %1, %2" : "=v"(pk) : "v"(p), "v"(p));
          Psh[w][(qf * 16 + lq * 4 + r) * 72 + kf * 16 + l15] = (unsigned short)pk;
        }
      }
    }

    // rescale decision (applied after PV: acc_new = alpha*(acc_old + P*V))
    bool need = false;
#pragma unroll
    for (int qf = 0; qf < 2; qf++)
#pragma unroll
      for (int r = 0; r < 4; r++)
        need = need || (tmax[qf][r] > mst[qf][r] + 8.0f);
    const bool resc = __any(need);
    float alpha[2][4];
    if (resc) {
#pragma unroll
      for (int m = 1; m < 16; m <<= 1)
#pragma unroll
        for (int qf = 0; qf < 2; qf++)
#pragma unroll
          for (int r = 0; r < 4; r++)
            tmax[qf][r] = fmaxf(tmax[qf][r], __shfl_xor(tmax[qf][r], m, 64));
#pragma unroll
      for (int qf = 0; qf < 2; qf++)
#pragma unroll
        for (int r = 0; r < 4; r++) {
          float mnew = fmaxf(mst[qf][r], tmax[qf][r]);
          alpha[qf][r] = fexp2((mst[qf][r] - mnew) * L2E);
          mst[qf][r] = mnew;
        }
    }

    __syncthreads();   // B1: all waves done reading K(t); drains V(t) loads

    // issue K(t+1); hides under PV
    if (kt + 64 < CHUNK) {
      const int ktB = (kt + 64) * 7680;
#pragma unroll
      for (int j = 0; j < 3; j++)
        if (kact[j]) gload16(kbase + kgo[j] + ktB, Kbuf + koff0 + j * 4096);
    }

    // PV (+ sum column)
    const unsigned short* Vsh = (const unsigned short*)Vbuf;
#pragma unroll
    for (int ks = 0; ks < 2; ks++) {
      bf16x8 pa[2];
#pragma unroll
      for (int qf = 0; qf < 2; qf++)
        pa[qf] = *reinterpret_cast<const bf16x8*>(&Psh[w][(qf * 16 + l15) * 72 + ks * 32 + lq * 8]);
#pragma unroll
      for (int df = 0; df < 5; df++) {
        bf16x8 vb = *reinterpret_cast<const bf16x8*>(&Vsh[(df * 16 + l15) * 72 + ks * 32 + lq * 8]);
#pragma unroll
        for (int qf = 0; qf < 2; qf++)
          acc[qf][df] = __builtin_amdgcn_mfma_f32_16x16x32_bf16(pa[qf], vb, acc[qf][df], 0, 0, 0);
      }
#pragma unroll
      for (int qf = 0; qf < 2; qf++)
        acc[qf][5] = __builtin_amdgcn_mfma_f32_16x16x32_bf16(pa[qf], onesb, acc[qf][5], 0, 0, 0);
    }

    // deferred rescale (rare)
    if (resc) {
#pragma unroll
      for (int qf = 0; qf < 2; qf++)
#pragma unroll
        for (int df = 0; df < 6; df++)
#pragma unroll
          for (int r = 0; r < 4; r++) acc[qf][df][r] *= alpha[qf][r];
    }

    __syncthreads();   // B2: all waves done reading V(t); drains K(t+1) loads

    // issue V(t+1); hides under next tile's QK^T + softmax
    if (kt + 64 < CHUNK) {
      const int ktV = (kt + 64) * 2;
#pragma unroll
      for (int j = 0; j < 3; j++)
        gload16(vbase + vgo[j] + ktV, Vbuf + vw * 1024 + j * 4096);
    }
  }

  // epilogue: out = acc / sum
  unsigned short* obase = outq + (size_t)(ch * CHUNK) * rs + head * HDIM;
#pragma unroll
  for (int qf = 0; qf < 2; qf++) {
    float inv[4];
#pragma unroll
    for (int r = 0; r < 4; r++) inv[r] = 1.0f / __shfl(acc[qf][5][r], lq * 16, 64);
#pragma unroll
    for (int df = 0; df < 5; df++) {
      int col = df * 16 + l15;
#pragma unroll
      for (int r = 0; r < 4; r++) {
        float v = acc[qf][df][r] * inv[r];
        obase[(size_t)(qr0 + qf * 16 + lq * 4 + r) * rs + col] = f2bf(v);
      }
    }
  }
}

extern "C" void kernel_launch(void* const* d_in, const int* in_sizes, int n_in,
                              void* d_out, int out_size, void* d_ws, size_t ws_size,
                              hipStream_t stream) {
  const float* hs    = (const float*)d_in[0];   // [8192][1280]
  const float* qkvw  = (const float*)d_in[2];   // [3840][1280]
  const float* qkvb  = (const float*)d_in[3];   // [3840]
  const float* projw = (const float*)d_in[4];   // [1280][1280]
  const float* projb = (const float*)d_in[5];   // [1280]

  char* ws = (char*)d_ws;
  unsigned short* hs_bf    = (unsigned short*)ws;                         // 20,971,520 B
  unsigned short* qkvw_bf  = (unsigned short*)(ws + 20971520);            //  9,830,400 B
  unsigned short* projw_bf = (unsigned short*)(ws + 20971520 + 9830400);  //  3,276,800 B
  unsigned short* qkv_bf   = (unsigned short*)(ws + 20971520 + 9830400 + 3276800); // 62,914,560 B
  // vT lives in d_out (41.9 MB fp32 buffer; scratch until proj GEMM overwrites it):
  // QKV-GEMM writes vT -> attn reads vT -> proj GEMM overwrites d_out. Stream-ordered.
  unsigned short* vT = (unsigned short*)d_out;  // 20,971,520 B needed

  cvt_f32_bf16<<<2048, 256, 0, stream>>>(hs,    hs_bf,    8192 * 1280 / 4);
  cvt_f32_bf16<<<1024, 256, 0, stream>>>(qkvw,  qkvw_bf,  3840 * 1280 / 4);
  cvt_f32_bf16<<<512,  256, 0, stream>>>(projw, projw_bf, 1280 * 1280 / 4);

  // qkv = hs @ qkv_w^T + qkv_b ; q cols pre-scaled (bf16 out); V cols -> vT transposed
  gemm_bt<<<dim3(30, 64), 256, 0, stream>>>(hs_bf, qkvw_bf, qkvb, qkv_bf, nullptr, vT,
                                            8192, 3840, 1280, 1280, 1280, QSCALE);
  // attention; output overwrites Q-columns of qkv_bf (XCD-swizzled 1-D grid)
  attn_kernel<<<dim3(1024), 256, 0, stream>>>(qkv_bf, vT, qkv_bf);
  // out = attn @ proj_w^T + proj_b (fp32 out), A has row stride 3840
  gemm_bt<<<dim3(10, 64), 256, 0, stream>>>(qkv_bf, projw_bf, projb,
                                            nullptr, (float*)d_out, nullptr,
                                            8192, 1280, 1280, 3840, 0, 1.0f);
}